// Round 2
// baseline (260.144 us; speedup 1.0000x reference)
//
#include <hip/hip_runtime.h>

// Reference: damped harmonic oscillator, RK4, 4096 steps, batch 16384.
// KEY INSIGHT 1: input x is unused except for batch size; all rows share
//   initial_state and (m,c,k) -> every output row is the SAME trajectory.
// KEY INSIGHT 2: linear ODE -> one RK4 step is a fixed 2x2 matrix M
//   (RK4 stability polynomial). out[b][t] = pos-component of M^(t+1) s0.
//   So the "sequential" scan is computed in parallel via matrix powers.

#define NUM_STEPS 4096
#define DT 0.01

struct dmat { double a, b, c, d; };   // [[a,b],[c,d]]

__device__ __forceinline__ dmat mmul(const dmat& x, const dmat& y) {
    dmat r;
    r.a = x.a * y.a + x.b * y.c;
    r.b = x.a * y.b + x.b * y.d;
    r.c = x.c * y.a + x.d * y.c;
    r.d = x.c * y.b + x.d * y.d;
    return r;
}

// One thread per output step t: traj[t] = pos of M^(t+1) * s0, in double
// (binary exponentiation, 13 bits). Double precision => essentially the
// exact RK4 map; reference's own f32 per-step rounding drift is larger.
__global__ __launch_bounds__(256) void traj_kernel(
        const float* __restrict__ m_, const float* __restrict__ c_,
        const float* __restrict__ k_, const float* __restrict__ s0,
        float* __restrict__ traj) {
    int t = blockIdx.x * blockDim.x + threadIdx.x;
    if (t >= NUM_STEPS) return;

    const double m = (double)m_[0];
    const double c = (double)c_[0];
    const double k = (double)k_[0];
    const double h = DT;
    const double a21 = -k / m, a22 = -c / m;

    dmat A  = {0.0, 1.0, a21, a22};
    dmat A2 = mmul(A, A);
    dmat A3 = mmul(A2, A);
    dmat A4 = mmul(A2, A2);
    const double h2 = h * h * 0.5;
    const double h3 = h * h * h / 6.0;
    const double h4 = h * h * h * h / 24.0;
    // M = I + hA + h^2/2 A^2 + h^3/6 A^3 + h^4/24 A^4
    dmat M = {1.0 + h * A.a + h2 * A2.a + h3 * A3.a + h4 * A4.a,
                    h * A.b + h2 * A2.b + h3 * A3.b + h4 * A4.b,
                    h * A.c + h2 * A2.c + h3 * A3.c + h4 * A4.c,
              1.0 + h * A.d + h2 * A2.d + h3 * A3.d + h4 * A4.d};

    int e = t + 1;                       // M^(t+1), e in [1, 4096]
    dmat R = {1.0, 0.0, 0.0, 1.0};
    dmat B = M;
    #pragma unroll
    for (int i = 0; i < 13; ++i) {
        if ((e >> i) & 1) R = mmul(R, B);
        B = mmul(B, B);
    }
    double pos = R.a * (double)s0[0] + R.b * (double)s0[1];
    traj[t] = (float)pos;
}

// Broadcast: out[b][t] = traj[t]. Each block owns a quarter-row column
// range (256 float4 = 4 KiB) and 16 rows; thread caches its float4 in a
// register, then does 16 fully-coalesced 1 KiB/wave stores.
__global__ __launch_bounds__(256) void bcast_kernel(
        const float4* __restrict__ traj4, float4* __restrict__ out4) {
    const int f = ((blockIdx.x & 3) << 8) + threadIdx.x;   // float4 col 0..1023
    const float4 v = traj4[f];
    float4* p = out4 + (size_t)(blockIdx.x >> 2) * 16 * 1024 + f;
    #pragma unroll
    for (int i = 0; i < 16; ++i)
        p[(size_t)i * 1024] = v;
}

extern "C" void kernel_launch(void* const* d_in, const int* in_sizes, int n_in,
                              void* d_out, int out_size, void* d_ws, size_t ws_size,
                              hipStream_t stream) {
    // inputs: x(16384*2) [unused], m(1), c(1), k(1), initial_state(2)
    const float* m_ = (const float*)d_in[1];
    const float* c_ = (const float*)d_in[2];
    const float* k_ = (const float*)d_in[3];
    const float* s0 = (const float*)d_in[4];
    float* traj = (float*)d_ws;                 // 4096 floats = 16 KiB
    float* out  = (float*)d_out;                // 16384*4096 floats

    traj_kernel<<<NUM_STEPS / 256, 256, 0, stream>>>(m_, c_, k_, s0, traj);

    // 16384 rows / 16 rows-per-block * 4 blocks-per-row-width = 4096 blocks
    bcast_kernel<<<4096, 256, 0, stream>>>((const float4*)traj, (float4*)out);
}